// Round 6
// baseline (130.356 us; speedup 1.0000x reference)
//
#include <hip/hip_runtime.h>

// Paged KV-cache scatter write (DeepSeek-V3 MLA):
//   out = k_cache; out[slot, :512] = key[tok]; out[slot, 512:] = value[tok]
// Fused gather-write: 16-bit inverse map slot->token in d_ws, then one
// streaming pass over the 302 MB output.
// R6: single-variable probe vs R5 — PLAIN stores (was NT). Completes the
// NT 2x2: {loads,stores} x {NT,cached}. R5 (cached loads + NT stores)=106.2us.

typedef float f32x4 __attribute__((ext_vector_type(4)));

constexpr int NUM_PAGES   = 512;
constexpr int PAGE_SIZE   = 256;
constexpr int CACHE_DIM   = 576;              // 512 lora + 64 rope
constexpr int LORA        = 512;
constexpr int ROPE        = 64;
constexpr int SLOTS       = NUM_PAGES * PAGE_SIZE;   // 131072
constexpr int V4_PER_SLOT = CACHE_DIM / 4;           // 144
constexpr int V4_LORA     = LORA / 4;                // 128
constexpr int V4_ROPE     = ROPE / 4;                // 16
constexpr int ITERS       = 4;                       // slot-iters per block
constexpr int SLOTS_PER_BLOCK = 16 * ITERS;          // 64

__global__ void fill_table_kernel(const int* __restrict__ page_idx,
                                  const int* __restrict__ page_offset,
                                  unsigned short* __restrict__ table, int T) {
    int t = blockIdx.x * blockDim.x + threadIdx.x;
    if (t < T) {
        int slot = page_idx[t] * PAGE_SIZE + page_offset[t];
        table[slot] = (unsigned short)t;      // T=16384 < 65536; 0xFFFF = untouched
    }
}

__global__ __launch_bounds__(256) void write_cache_kernel(
        const f32x4* __restrict__ kc,
        const f32x4* __restrict__ ks,
        const f32x4* __restrict__ vs,
        const unsigned short* __restrict__ table,
        f32x4* __restrict__ out) {
    const int tid = threadIdx.x;
    const int grp = tid >> 4;                 // 16 groups of 16 lanes
    const int sub = tid & 15;

#pragma unroll
    for (int it = 0; it < ITERS; ++it) {
        const int slot  = blockIdx.x * SLOTS_PER_BLOCK + it * 16 + grp;
        const int tok   = table[slot];        // broadcast across 16 lanes
        const int obase = slot * V4_PER_SLOT;
        const bool touched = (tok != 0xFFFF);

        // Uniform-per-thread source pointers (cndmask, no branch):
        const f32x4* pmain = touched ? (ks + (tok * V4_LORA + sub))
                                     : (kc + (obase + sub));
        const f32x4* plast = touched ? (vs + (tok * V4_ROPE + sub))
                                     : (kc + (obase + V4_LORA + sub));

        f32x4 r[9];
#pragma unroll
        for (int k = 0; k < 8; ++k)
            r[k] = pmain[k * 16];             // cached loads, 9 in flight
        r[8] = *plast;

#pragma unroll
        for (int k = 0; k < 8; ++k)
            out[obase + sub + k * 16] = r[k];  // plain stores (probe)
        out[obase + V4_LORA + sub] = r[8];
    }
}

// Fallback path if d_ws can't hold the inverse table: full D2D copy + scatter.
__global__ void scatter_kernel(const f32x4* __restrict__ ks,
                               const f32x4* __restrict__ vs,
                               const int* __restrict__ page_idx,
                               const int* __restrict__ page_offset,
                               f32x4* __restrict__ out, int T) {
    int total = T * V4_PER_SLOT;
    int g = blockIdx.x * blockDim.x + threadIdx.x;
    if (g >= total) return;
    int t = g / V4_PER_SLOT;
    int j = g - t * V4_PER_SLOT;
    int slot = page_idx[t] * PAGE_SIZE + page_offset[t];
    f32x4 val = (j < V4_LORA) ? ks[t * V4_LORA + j]
                              : vs[t * V4_ROPE + (j - V4_LORA)];
    out[(long)slot * V4_PER_SLOT + j] = val;
}

extern "C" void kernel_launch(void* const* d_in, const int* in_sizes, int n_in,
                              void* d_out, int out_size, void* d_ws, size_t ws_size,
                              hipStream_t stream) {
    const f32x4* kc   = (const f32x4*)d_in[0];    // k_cache   [512,256,1,576] f32
    const f32x4* ks   = (const f32x4*)d_in[1];    // key_states   [T,512] f32
    const f32x4* vs   = (const f32x4*)d_in[2];    // value_states [T,64]  f32
    const int* pidx   = (const int*)d_in[3];      // page_idx    [T]
    const int* poff   = (const int*)d_in[4];      // page_offset [T]
    f32x4* out        = (f32x4*)d_out;
    const int T       = in_sizes[3];

    if (ws_size >= (size_t)SLOTS * sizeof(unsigned short)) {
        unsigned short* table = (unsigned short*)d_ws;
        // 0xFF bytes == 0xFFFF sentinel in every u16 slot ("untouched").
        // Rebuilt every call (no reliance on d_ws state across replays).
        (void)hipMemsetAsync(table, 0xFF, (size_t)SLOTS * sizeof(unsigned short), stream);
        fill_table_kernel<<<(T + 255) / 256, 256, 0, stream>>>(pidx, poff, table, T);
        write_cache_kernel<<<SLOTS / SLOTS_PER_BLOCK, 256, 0, stream>>>(
            kc, ks, vs, table, out);
    } else {
        (void)hipMemcpyAsync(d_out, d_in[0], (size_t)SLOTS * CACHE_DIM * sizeof(float),
                             hipMemcpyDeviceToDevice, stream);
        int total = T * V4_PER_SLOT;
        scatter_kernel<<<(total + 255) / 256, 256, 0, stream>>>(ks, vs, pidx, poff, out, T);
    }
}

// Round 7
// 105.669 us; speedup vs baseline: 1.2336x; 1.2336x over previous
//
#include <hip/hip_runtime.h>

// Paged KV-cache scatter write (DeepSeek-V3 MLA):
//   out = k_cache; out[slot, :512] = key[tok]; out[slot, 512:] = value[tok]
// Fused gather-write: 16-bit inverse map slot->token in d_ws, then one
// streaming pass over the 302 MB output.
// FINAL config (R5, reproduced): cached loads + NT stores.
//   NT 2x2 measured: cached/cached=129.5, NT/NT=121.0, cached/NT=106.2,
//   cached-loads/plain-stores=130.4. NT belongs on the dead write stream
//   only; loads need L2 read-buffering.

typedef float f32x4 __attribute__((ext_vector_type(4)));

constexpr int NUM_PAGES   = 512;
constexpr int PAGE_SIZE   = 256;
constexpr int CACHE_DIM   = 576;              // 512 lora + 64 rope
constexpr int LORA        = 512;
constexpr int ROPE        = 64;
constexpr int SLOTS       = NUM_PAGES * PAGE_SIZE;   // 131072
constexpr int V4_PER_SLOT = CACHE_DIM / 4;           // 144
constexpr int V4_LORA     = LORA / 4;                // 128
constexpr int V4_ROPE     = ROPE / 4;                // 16
constexpr int ITERS       = 4;                       // slot-iters per block
constexpr int SLOTS_PER_BLOCK = 16 * ITERS;          // 64

__global__ void fill_table_kernel(const int* __restrict__ page_idx,
                                  const int* __restrict__ page_offset,
                                  unsigned short* __restrict__ table, int T) {
    int t = blockIdx.x * blockDim.x + threadIdx.x;
    if (t < T) {
        int slot = page_idx[t] * PAGE_SIZE + page_offset[t];
        table[slot] = (unsigned short)t;      // T=16384 < 65536; 0xFFFF = untouched
    }
}

__global__ __launch_bounds__(256) void write_cache_kernel(
        const f32x4* __restrict__ kc,
        const f32x4* __restrict__ ks,
        const f32x4* __restrict__ vs,
        const unsigned short* __restrict__ table,
        f32x4* __restrict__ out) {
    const int tid = threadIdx.x;
    const int grp = tid >> 4;                 // 16 groups of 16 lanes
    const int sub = tid & 15;

#pragma unroll
    for (int it = 0; it < ITERS; ++it) {
        const int slot  = blockIdx.x * SLOTS_PER_BLOCK + it * 16 + grp;
        const int tok   = table[slot];        // broadcast across 16 lanes
        const int obase = slot * V4_PER_SLOT;
        const bool touched = (tok != 0xFFFF);

        // Uniform-per-thread source pointers (cndmask, no branch):
        const f32x4* pmain = touched ? (ks + (tok * V4_LORA + sub))
                                     : (kc + (obase + sub));
        const f32x4* plast = touched ? (vs + (tok * V4_ROPE + sub))
                                     : (kc + (obase + V4_LORA + sub));

        f32x4 r[9];
#pragma unroll
        for (int k = 0; k < 8; ++k)
            r[k] = pmain[k * 16];             // cached loads, 9 in flight
        r[8] = *plast;

#pragma unroll
        for (int k = 0; k < 8; ++k)
            __builtin_nontemporal_store(r[k], out + obase + sub + k * 16);
        __builtin_nontemporal_store(r[8], out + obase + V4_LORA + sub);
    }
}

// Fallback path if d_ws can't hold the inverse table: full D2D copy + scatter.
__global__ void scatter_kernel(const f32x4* __restrict__ ks,
                               const f32x4* __restrict__ vs,
                               const int* __restrict__ page_idx,
                               const int* __restrict__ page_offset,
                               f32x4* __restrict__ out, int T) {
    int total = T * V4_PER_SLOT;
    int g = blockIdx.x * blockDim.x + threadIdx.x;
    if (g >= total) return;
    int t = g / V4_PER_SLOT;
    int j = g - t * V4_PER_SLOT;
    int slot = page_idx[t] * PAGE_SIZE + page_offset[t];
    f32x4 val = (j < V4_LORA) ? ks[t * V4_LORA + j]
                              : vs[t * V4_ROPE + (j - V4_LORA)];
    out[(long)slot * V4_PER_SLOT + j] = val;
}

extern "C" void kernel_launch(void* const* d_in, const int* in_sizes, int n_in,
                              void* d_out, int out_size, void* d_ws, size_t ws_size,
                              hipStream_t stream) {
    const f32x4* kc   = (const f32x4*)d_in[0];    // k_cache   [512,256,1,576] f32
    const f32x4* ks   = (const f32x4*)d_in[1];    // key_states   [T,512] f32
    const f32x4* vs   = (const f32x4*)d_in[2];    // value_states [T,64]  f32
    const int* pidx   = (const int*)d_in[3];      // page_idx    [T]
    const int* poff   = (const int*)d_in[4];      // page_offset [T]
    f32x4* out        = (f32x4*)d_out;
    const int T       = in_sizes[3];

    if (ws_size >= (size_t)SLOTS * sizeof(unsigned short)) {
        unsigned short* table = (unsigned short*)d_ws;
        // 0xFF bytes == 0xFFFF sentinel in every u16 slot ("untouched").
        // Rebuilt every call (d_ws is poisoned to 0xAA before timing; no
        // reliance on d_ws state across replays).
        (void)hipMemsetAsync(table, 0xFF, (size_t)SLOTS * sizeof(unsigned short), stream);
        fill_table_kernel<<<(T + 255) / 256, 256, 0, stream>>>(pidx, poff, table, T);
        write_cache_kernel<<<SLOTS / SLOTS_PER_BLOCK, 256, 0, stream>>>(
            kc, ks, vs, table, out);
    } else {
        (void)hipMemcpyAsync(d_out, d_in[0], (size_t)SLOTS * CACHE_DIM * sizeof(float),
                             hipMemcpyDeviceToDevice, stream);
        int total = T * V4_PER_SLOT;
        scatter_kernel<<<(total + 255) / 256, 256, 0, stream>>>(ks, vs, pidx, poff, out, T);
    }
}